// Round 1
// baseline (1356.388 us; speedup 1.0000x reference)
//
#include <hip/hip_runtime.h>
#include <stdint.h>

#define B_   8
#define T_   1024
#define CIN_ 4096
#define CH_  4096

// ---------------- helpers ----------------

// per-byte nonzero -> 0x01, packed
__device__ __forceinline__ uint32_t bytes_nonzero01(uint32_t w) {
  uint32_t t = (w & 0x7F7F7F7Fu) + 0x7F7F7F7Fu;
  t = (t | w) & 0x80808080u;
  return t >> 7;
}

// load 4 consecutive boolean elements (elements idx4*4 .. idx4*4+3) from a
// buffer whose element size is es (1, 2 or 4 bytes); return packed bytes 0/1.
__device__ __forceinline__ uint32_t load4(const void* base, long idx4, int es) {
  if (es == 1) {
    uint32_t w = ((const uint32_t*)base)[idx4];
    return bytes_nonzero01(w);
  } else if (es == 2) {
    uint32_t w0 = ((const uint32_t*)base)[idx4 * 2];
    uint32_t w1 = ((const uint32_t*)base)[idx4 * 2 + 1];
    uint32_t r = 0;
    r |= ((w0 & 0xFFFFu) != 0u) ? 0x00000001u : 0u;
    r |= ((w0 >> 16)     != 0u) ? 0x00000100u : 0u;
    r |= ((w1 & 0xFFFFu) != 0u) ? 0x00010000u : 0u;
    r |= ((w1 >> 16)     != 0u) ? 0x01000000u : 0u;
    return r;
  } else {
    uint4 w = ((const uint4*)base)[idx4];
    uint32_t r = 0;
    r |= (w.x != 0u) ? 0x00000001u : 0u;
    r |= (w.y != 0u) ? 0x00000100u : 0u;
    r |= (w.z != 0u) ? 0x00010000u : 0u;
    r |= (w.w != 0u) ? 0x01000000u : 0u;
    return r;
  }
}

// expand 4 packed 0/1 bytes into 4 int32 0/1
__device__ __forceinline__ uint4 expand01(uint32_t v4) {
  uint4 r = { v4 & 1u, (v4 >> 8) & 1u, (v4 >> 16) & 1u, (v4 >> 24) & 1u };
  return r;
}

// ---------------- kernel 1 (+0): fan-in index extraction, detect folded in ----
// Blocks 0..2047: one wave per row; rows 0..4095 = A_input, 4096..8191 = A_hidden.
// Block 2048: encoding detection (round-1 evidence: harness uses int32 for bool
// arrays -> mode=4; kept for robustness). Folding removes one serial launch gap.
__global__ __launch_bounds__(256) void extract_kernel(const float* __restrict__ Ain,
                                                      const float* __restrict__ Ah,
                                                      uint32_t* __restrict__ idxin,
                                                      uint32_t* __restrict__ idxh,
                                                      const uint32_t* __restrict__ z,
                                                      uint32_t* __restrict__ modep) {
  if (blockIdx.x == 2048) {
    // ---- detect (threads 0..255) ----
    __shared__ int sB, sH, sW, sL;
    const int n = threadIdx.x;
    if (n == 0) { sB = 1; sH = 1; sW = 1; sL = 0; }
    __syncthreads();
    int okB = 1, okH = 1, okW = 1, low = 0;
    for (int k = 0; k < 16; ++k) {
      uint32_t w = z[n + 256 * k];
      if ((w & 0xFEFEFEFEu) != 0u) okB = 0;                    // bytes in {0,1}?
      uint32_t lo = w & 0xFFFFu, hi = w >> 16;
      if (!((lo == 0u || lo == 0x3F80u) && (hi == 0u || hi == 0x3F80u))) okH = 0;
      if (!(w == 0u || w == 1u)) okW = 0;                      // words in {0,1}?
      if (lo != 0u) low = 1;                                   // f32 has low half 0
    }
    if (!okB) atomicAnd(&sB, 0);
    if (!okH) atomicAnd(&sH, 0);
    if (!okW) atomicAnd(&sW, 0);
    if (low)  atomicOr(&sL, 1);
    __syncthreads();
    if (n == 0) {
      uint32_t mode;
      if (sW)      mode = 4;              // int32 0/1
      else if (sB) mode = 1;              // uint8 bool
      else if (sH) mode = sL ? 2 : 4;     // bf16 : float32
      else         mode = 1;              // fallback (shouldn't happen)
      modep[0] = mode;
    }
    return;
  }
  // ---- extract: full-row scan, LDS atomic slot counter (order irrelevant) ----
  const int wave = threadIdx.x >> 6;
  const int lane = threadIdx.x & 63;
  const int row  = blockIdx.x * 4 + wave;   // 0..8191
  const float* A;
  uint32_t* outp;
  if (row < 4096) { A = Ain + (long)row * 4096;          outp = idxin + row * 3; }
  else            { A = Ah  + (long)(row - 4096) * 4096; outp = idxh + (row - 4096) * 3; }
  __shared__ int cnt[4];
  if (lane == 0) cnt[wave] = 0;
  __syncthreads();
  const float4* A4 = (const float4*)A;
  #pragma unroll
  for (int it = 0; it < 16; ++it) {
    float4 v = A4[it * 64 + lane];          // cols 4*(it*64+lane) .. +3
    int cbase = (it * 64 + lane) * 4;
    if (v.x != 0.0f) { int p = atomicAdd(&cnt[wave], 1); if (p < 3) outp[p] = cbase;     }
    if (v.y != 0.0f) { int p = atomicAdd(&cnt[wave], 1); if (p < 3) outp[p] = cbase + 1; }
    if (v.z != 0.0f) { int p = atomicAdd(&cnt[wave], 1); if (p < 3) outp[p] = cbase + 2; }
    if (v.w != 0.0f) { int p = atomicAdd(&cnt[wave], 1); if (p < 3) outp[p] = cbase + 3; }
  }
}

// ---------------- kernel 2: input-OR precompute + z-copy + gather SCHEDULING --
// Blocks 0..1023: in_orb byte [t][i] = bit b set iff (z[b,t,c0]|z[b,t,c1]|z[b,t,c2]).
//   Also writes the z-half of out (int32 0/1) — z is only read ONCE total.
// Block 1024 (hidden behind the memory-bound blocks): conflict-aware gather
//   SCHEDULE for scan_kernel. The scan's 12 LDS byte-gathers per thread have
//   STATIC addresses (fan-in fixed across all 1024 steps) -> its ~406 bank-
//   conflict cycles/step repeat identically. Reorder each lane's 12 reads
//   across the 12 issue slots so each (wave-op, bank) gets <=2 lanes (free).
//   Output (reusing the idxh region, 32KB<=48KB): per scan-thread 8 dwords:
//   words 0..5 = 12 slot-ordered u16 LDS byte-addrs, word 6 = 12x2b shift codes.
__global__ __launch_bounds__(1024) void inor_kernel(const void* __restrict__ z,
                                                    const uint32_t* __restrict__ idxin,
                                                    const uint32_t* __restrict__ idxh,
                                                    const uint32_t* __restrict__ modep,
                                                    uint32_t* __restrict__ in_orb,
                                                    uint32_t* __restrict__ out) {
  __shared__ __align__(16) unsigned char zp[4096];     // batch-packed z row
  __shared__ uint16_t cnt[16][12][32];                 // sched: per-wave slot x bank load

  if (blockIdx.x == T_) {
    // ================= gather scheduler =================
    const int n  = threadIdx.x;        // == scan thread id 0..1023
    const int wv = n >> 6, ln = n & 63;
    // my 12 entries: entry e -> source neuron d[e], dest sub-neuron j = e/3
    const uint4* p = (const uint4*)(idxh + n * 12);
    uint4 q0 = p[0], q1 = p[1], q2 = p[2];
    uint32_t d[12] = { q0.x, q0.y, q0.z,  q0.w, q1.x, q1.y,
                       q1.z, q1.w, q2.x,  q2.y, q2.z, q2.w };
    // zero my wave's counters
    for (int i = threadIdx.x; i < 16 * 12 * 32; i += 1024) ((uint16_t*)cnt)[i] = 0;
    __syncthreads();
    // lane-serial greedy within each wave: assign each entry to the free slot
    // whose (slot,bank) load is minimal. 64 lanes x 12 entries x <=12 slots.
    int slotOf[12];
    uint32_t freem = 0xFFFu;
    for (int l = 0; l < 64; ++l) {
      if (ln == l) {
        #pragma unroll
        for (int e = 0; e < 12; ++e) {
          uint32_t bank = (d[e] >> 2) & 31u;
          int best = 0; uint32_t bc = 0xFFFFFFFFu;
          #pragma unroll
          for (int k = 0; k < 12; ++k) {
            if ((freem >> k) & 1u) {
              uint32_t c = cnt[wv][k][bank];
              if (c < bc) { bc = c; best = k; }
            }
          }
          slotOf[e] = best;
          freem &= ~(1u << best);
          cnt[wv][best][bank] = (uint16_t)(cnt[wv][best][bank] + 1);
        }
      }
    }
    __syncthreads();   // all idxh reads done before overwrite below
    // compose slot-ordered output (static-indexed select chains; no scratch)
    uint32_t wv6[6]; uint32_t S = 0;
    #pragma unroll
    for (int k = 0; k < 12; ++k) {
      uint32_t de = 0, je = 0;
      #pragma unroll
      for (int e = 0; e < 12; ++e) {
        bool m = (slotOf[e] == k);
        de = m ? d[e] : de;
        je = m ? (uint32_t)(e / 3) : je;
      }
      if (k & 1) wv6[k >> 1] |= de << 16; else wv6[k >> 1] = de;
      S |= je << (2 * k);
    }
    uint4* o4 = (uint4*)((uint32_t*)idxh + (size_t)n * 8);   // reuse idxh region
    o4[0] = make_uint4(wv6[0], wv6[1], wv6[2], wv6[3]);
    o4[1] = make_uint4(wv6[4], wv6[5], S, 0u);
    return;
  }

  // ================= normal in-OR path =================
  const int t = blockIdx.x;
  const int n = threadIdx.x;
  const int es = (int)modep[0];
  uint32_t acc = 0;
  #pragma unroll
  for (int b = 0; b < B_; ++b) {
    uint32_t v4 = load4(z, ((long)b * T_ + t) * 1024 + n, es);
    acc |= v4 << b;
    ((uint4*)(out + ((long)b * T_ + t) * 8192))[n] = expand01(v4);
  }
  ((uint32_t*)zp)[n] = acc;
  __syncthreads();
  const uint4* ip = (const uint4*)(idxin + n * 12);  // indices for neurons 4n..4n+3
  uint4 q0 = ip[0], q1 = ip[1], q2 = ip[2];
  uint32_t r0 = (uint32_t)zp[q0.x] | zp[q0.y] | zp[q0.z];
  uint32_t r1 = (uint32_t)zp[q0.w] | zp[q1.x] | zp[q1.y];
  uint32_t r2 = (uint32_t)zp[q1.z] | zp[q1.w] | zp[q2.x];
  uint32_t r3 = (uint32_t)zp[q2.y] | zp[q2.z] | zp[q2.w];
  in_orb[t * 1024 + n] = r0 | (r1 << 8) | (r2 << 16) | (r3 << 24);
}

// ---------------- kernel 3: sequential scan (the recurrence) ----------------
// 8 blocks, one per batch. h kept as 4096 bytes in double-buffered LDS.
// DS-pipe bound: 192 byte-gather + 16 word-write wave-ops/step. This round:
// gathers follow the conflict-minimized slot schedule (static addresses ->
// static conflicts -> schedulable away); inner loop is branch-free shift-OR
// with the in-mask applied once at the end (bytes are 0/1 so AND == per-
// neuron gating). 2-step unroll bakes the double-buffer phase into two
// precomputed address sets (aA / aB = aA+4096).
__global__ __launch_bounds__(1024) void scan_kernel(const uint32_t* __restrict__ in_orb,
                                                    const uint32_t* __restrict__ sched,
                                                    const void* __restrict__ h0,
                                                    const uint32_t* __restrict__ modep,
                                                    uint32_t* __restrict__ out) {
  const int b = blockIdx.x;
  const int n = threadIdx.x;
  const int es = (int)modep[0];
  __shared__ __align__(128) unsigned char hbuf[2][4096];

  // slot-ordered gather schedule -> registers (loop-invariant)
  const uint4* sp = (const uint4*)(sched + (size_t)n * 8);
  uint4 s0 = sp[0], s1 = sp[1];
  uint32_t aw[6] = { s0.x, s0.y, s0.z, s0.w, s1.x, s1.y };
  uint32_t aA[12], aB[12], sh[12];
  #pragma unroll
  for (int e = 0; e < 12; ++e) {
    uint32_t a = (aw[e >> 1] >> ((e & 1) * 16)) & 0xFFFFu;
    aA[e] = a; aB[e] = a + 4096u;
    sh[e] = ((s1.z >> (2 * e)) & 3u) * 8u;
  }

  unsigned char* lds8 = &hbuf[0][0];
  // init h(-1) = h0[b] into buf0
  ((uint32_t*)lds8)[n] = load4(h0, (long)b * 1024 + n, es);
  __syncthreads();

  uint32_t* outh = out + (long)b * T_ * 8192 + 4096;  // h-half of out for batch b

  uint32_t inw0 = in_orb[n];   // t = 0 (prefetched)
  for (int t = 0; t < T_; t += 2) {
    uint32_t inw1 = in_orb[(t + 1) * 1024 + n];
    // ---- step t: read buf0 (aA), write buf1
    uint32_t o = 0;
    #pragma unroll
    for (int e = 0; e < 12; ++e) o |= ((uint32_t)lds8[aA[e]]) << sh[e];
    o &= (inw0 >> b) & 0x01010101u;
    ((uint32_t*)(lds8 + 4096))[n] = o;                       // bytes 0/1
    ((uint4*)(outh + (long)t * 8192))[n] = expand01(o);      // fire-and-forget
    __syncthreads();
    uint32_t inw2 = (t + 2 < T_) ? in_orb[(t + 2) * 1024 + n] : 0u;
    // ---- step t+1: read buf1 (aB), write buf0
    uint32_t o2 = 0;
    #pragma unroll
    for (int e = 0; e < 12; ++e) o2 |= ((uint32_t)lds8[aB[e]]) << sh[e];
    o2 &= (inw1 >> b) & 0x01010101u;
    ((uint32_t*)lds8)[n] = o2;
    ((uint4*)(outh + (long)(t + 1) * 8192))[n] = expand01(o2);
    __syncthreads();
    inw0 = inw2;
  }
}

// ---------------- launch ----------------
extern "C" void kernel_launch(void* const* d_in, const int* in_sizes, int n_in,
                              void* d_out, int out_size, void* d_ws, size_t ws_size,
                              hipStream_t stream) {
  const void*  z   = d_in[0];                 // bool (B,T,CIN) - int32 0/1 (detected)
  const void*  h0  = d_in[1];                 // bool (B,CH)
  const float* Ain = (const float*)d_in[2];   // (CH,CIN) f32
  const float* Ah  = (const float*)d_in[3];   // (CH,CH)  f32
  uint32_t* out = (uint32_t*)d_out;           // int32 0/1

  char* ws = (char*)d_ws;
  // ws layout (bytes): [0] mode | [256] idx_in 48K | [49408] idx_h 48K (becomes
  //                    32K gather SCHEDULE after inor block 1024) | [98560] in_orb 4MiB
  uint32_t* modep = (uint32_t*)(ws);
  uint32_t* idxin = (uint32_t*)(ws + 256);
  uint32_t* idxh  = (uint32_t*)(ws + 256 + 49152);
  uint32_t* inorb = (uint32_t*)(ws + 98560);
  uint32_t* sched = idxh;                     // scheduler overwrites idxh in place

  extract_kernel<<<2049, 256,  0, stream>>>(Ain, Ah, idxin, idxh,
                                            (const uint32_t*)z, modep);
  inor_kernel   <<<T_ + 1, 1024, 0, stream>>>(z, idxin, idxh, modep, inorb, out);
  scan_kernel   <<<B_,   1024, 0, stream>>>(inorb, sched, h0, modep, out);
}

// Round 2
// 1141.316 us; speedup vs baseline: 1.1884x; 1.1884x over previous
//
#include <hip/hip_runtime.h>
#include <stdint.h>

#define B_   8
#define T_   1024
#define CIN_ 4096
#define CH_  4096
#define RCAP 1920   // records per (b,t); mean ~1581, sigma ~31 -> ~11 sigma headroom

// ---------------- helpers ----------------

// per-byte nonzero -> 0x01, packed
__device__ __forceinline__ uint32_t bytes_nonzero01(uint32_t w) {
  uint32_t t = (w & 0x7F7F7F7Fu) + 0x7F7F7F7Fu;
  t = (t | w) & 0x80808080u;
  return t >> 7;
}

// load 4 consecutive boolean elements (elements idx4*4 .. idx4*4+3) from a
// buffer whose element size is es (1, 2 or 4 bytes); return packed bytes 0/1.
__device__ __forceinline__ uint32_t load4(const void* base, long idx4, int es) {
  if (es == 1) {
    uint32_t w = ((const uint32_t*)base)[idx4];
    return bytes_nonzero01(w);
  } else if (es == 2) {
    uint32_t w0 = ((const uint32_t*)base)[idx4 * 2];
    uint32_t w1 = ((const uint32_t*)base)[idx4 * 2 + 1];
    uint32_t r = 0;
    r |= ((w0 & 0xFFFFu) != 0u) ? 0x00000001u : 0u;
    r |= ((w0 >> 16)     != 0u) ? 0x00000100u : 0u;
    r |= ((w1 & 0xFFFFu) != 0u) ? 0x00010000u : 0u;
    r |= ((w1 >> 16)     != 0u) ? 0x01000000u : 0u;
    return r;
  } else {
    uint4 w = ((const uint4*)base)[idx4];
    uint32_t r = 0;
    r |= (w.x != 0u) ? 0x00000001u : 0u;
    r |= (w.y != 0u) ? 0x00000100u : 0u;
    r |= (w.z != 0u) ? 0x00010000u : 0u;
    r |= (w.w != 0u) ? 0x01000000u : 0u;
    return r;
  }
}

// expand 4 packed 0/1 bytes into 4 int32 0/1
__device__ __forceinline__ uint4 expand01(uint32_t v4) {
  uint4 r = { v4 & 1u, (v4 >> 8) & 1u, (v4 >> 16) & 1u, (v4 >> 24) & 1u };
  return r;
}

// ---------------- kernel 1 (+0): fan-in index extraction, detect folded in ----
// Blocks 0..2047: one wave per row; rows 0..4095 = A_input, 4096..8191 = A_hidden.
// Block 2048: encoding detection (round-1 evidence: harness uses int32 for bool
// arrays -> mode=4; kept for robustness).
__global__ __launch_bounds__(256) void extract_kernel(const float* __restrict__ Ain,
                                                      const float* __restrict__ Ah,
                                                      uint32_t* __restrict__ idxin,
                                                      uint32_t* __restrict__ idxh,
                                                      const uint32_t* __restrict__ z,
                                                      uint32_t* __restrict__ modep) {
  if (blockIdx.x == 2048) {
    __shared__ int sB, sH, sW, sL;
    const int n = threadIdx.x;
    if (n == 0) { sB = 1; sH = 1; sW = 1; sL = 0; }
    __syncthreads();
    int okB = 1, okH = 1, okW = 1, low = 0;
    for (int k = 0; k < 16; ++k) {
      uint32_t w = z[n + 256 * k];
      if ((w & 0xFEFEFEFEu) != 0u) okB = 0;
      uint32_t lo = w & 0xFFFFu, hi = w >> 16;
      if (!((lo == 0u || lo == 0x3F80u) && (hi == 0u || hi == 0x3F80u))) okH = 0;
      if (!(w == 0u || w == 1u)) okW = 0;
      if (lo != 0u) low = 1;
    }
    if (!okB) atomicAnd(&sB, 0);
    if (!okH) atomicAnd(&sH, 0);
    if (!okW) atomicAnd(&sW, 0);
    if (low)  atomicOr(&sL, 1);
    __syncthreads();
    if (n == 0) {
      uint32_t mode;
      if (sW)      mode = 4;
      else if (sB) mode = 1;
      else if (sH) mode = sL ? 2 : 4;
      else         mode = 1;
      modep[0] = mode;
    }
    return;
  }
  const int wave = threadIdx.x >> 6;
  const int lane = threadIdx.x & 63;
  const int row  = blockIdx.x * 4 + wave;   // 0..8191
  const float* A;
  uint32_t* outp;
  if (row < 4096) { A = Ain + (long)row * 4096;          outp = idxin + row * 3; }
  else            { A = Ah  + (long)(row - 4096) * 4096; outp = idxh + (row - 4096) * 3; }
  __shared__ int cnt[4];
  if (lane == 0) cnt[wave] = 0;
  __syncthreads();
  const float4* A4 = (const float4*)A;
  #pragma unroll
  for (int it = 0; it < 16; ++it) {
    float4 v = A4[it * 64 + lane];
    int cbase = (it * 64 + lane) * 4;
    if (v.x != 0.0f) { int p = atomicAdd(&cnt[wave], 1); if (p < 3) outp[p] = cbase;     }
    if (v.y != 0.0f) { int p = atomicAdd(&cnt[wave], 1); if (p < 3) outp[p] = cbase + 1; }
    if (v.z != 0.0f) { int p = atomicAdd(&cnt[wave], 1); if (p < 3) outp[p] = cbase + 2; }
    if (v.w != 0.0f) { int p = atomicAdd(&cnt[wave], 1); if (p < 3) outp[p] = cbase + 3; }
  }
}

// ---------------- kernel 2: input-OR + z-copy + ACTIVE-RECORD build ----------
// Blocks 0..1023 (per t):
//  (a) in_orb byte [t][i] bit b = OR of batch-b z over input fan-in (as before);
//      also writes the z-half of out (z read ONCE total).
//  (b) NEW: for each batch b, compact the active neurons (in-bit = 1, density
//      0.386) into records {dst,u16 s0,s1,s2} — precomputed gather work for the
//      scan. Position = ballot-based prefix rank (lane-major, j-minor), so
//      neighboring threads write adjacent records (coalesces in L2).
//      Round-1 lesson: scan is DS-ISSUE-COUNT bound (~5.8 cyc/wave-op); only
//      fewer ops help. Records cut scan from 208 -> ~124 DS ops/step.
__global__ __launch_bounds__(1024) void inor_kernel(const void* __restrict__ z,
                                                    const uint32_t* __restrict__ idxin,
                                                    const uint32_t* __restrict__ idxh,
                                                    const uint32_t* __restrict__ modep,
                                                    uint32_t* __restrict__ in_orb,
                                                    uint32_t* __restrict__ out,
                                                    uint2* __restrict__ recs,
                                                    uint32_t* __restrict__ actcnt) {
  const int t = blockIdx.x;
  const int n = threadIdx.x;
  const int lane = n & 63, wv = n >> 6;
  const int es = (int)modep[0];
  __shared__ __align__(16) unsigned char zp[4096];   // batch-packed z row
  __shared__ uint32_t wsum[B_][16];                  // per-batch per-wave active counts

  uint32_t acc = 0;
  #pragma unroll
  for (int b = 0; b < B_; ++b) {
    uint32_t v4 = load4(z, ((long)b * T_ + t) * 1024 + n, es);
    acc |= v4 << b;
    ((uint4*)(out + ((long)b * T_ + t) * 8192))[n] = expand01(v4);
  }
  ((uint32_t*)zp)[n] = acc;
  __syncthreads();
  const uint4* ip = (const uint4*)(idxin + n * 12);  // input fan-in, neurons 4n..4n+3
  uint4 q0 = ip[0], q1 = ip[1], q2 = ip[2];
  uint32_t r0 = (uint32_t)zp[q0.x] | zp[q0.y] | zp[q0.z];
  uint32_t r1 = (uint32_t)zp[q0.w] | zp[q1.x] | zp[q1.y];
  uint32_t r2 = (uint32_t)zp[q1.z] | zp[q1.w] | zp[q2.x];
  uint32_t r3 = (uint32_t)zp[q2.y] | zp[q2.z] | zp[q2.w];
  uint32_t w = r0 | (r1 << 8) | (r2 << 16) | (r3 << 24);
  in_orb[t * 1024 + n] = w;

  if (recs == nullptr) return;   // fallback mode (workspace too small)

  // ---- record build ----
  // hidden fan-in for my 4 neurons (u32 triplets from extract)
  const uint4* hp = (const uint4*)(idxh + n * 12);
  uint4 h0q = hp[0], h1q = hp[1], h2q = hp[2];
  const uint32_t s00 = h0q.x, s01 = h0q.y, s02 = h0q.z;
  const uint32_t s10 = h0q.w, s11 = h1q.x, s12 = h1q.y;
  const uint32_t s20 = h1q.z, s21 = h1q.w, s22 = h2q.x;
  const uint32_t s30 = h2q.y, s31 = h2q.z, s32 = h2q.w;

  uint32_t mB[B_], exB[B_];
  const uint64_t ltm = (1ull << lane) - 1ull;
  #pragma unroll
  for (int b = 0; b < B_; ++b) {
    uint32_t m = (w >> b) & 0x01010101u;
    mB[b] = m;
    uint32_t ex = 0, tot = 0;
    #pragma unroll
    for (int j = 0; j < 4; ++j) {
      uint64_t bl = __ballot((m >> (8 * j)) & 1u);
      ex  += (uint32_t)__popcll(bl & ltm);
      tot += (uint32_t)__popcll(bl);
    }
    exB[b] = ex;
    if (lane == 0) wsum[b][wv] = tot;
  }
  __syncthreads();
  #pragma unroll
  for (int b = 0; b < B_; ++b) {
    uint32_t base = exB[b];
    for (int wq = 0; wq < wv; ++wq) base += wsum[b][wq];
    uint2* rb = recs + ((size_t)b * T_ + t) * RCAP;
    uint32_t m = mB[b];
    uint32_t pos = base;
    if (m & 0x00000001u) { if (pos < RCAP) rb[pos] = make_uint2((uint32_t)(4*n+0) | (s00 << 16), s01 | (s02 << 16)); pos++; }
    if (m & 0x00000100u) { if (pos < RCAP) rb[pos] = make_uint2((uint32_t)(4*n+1) | (s10 << 16), s11 | (s12 << 16)); pos++; }
    if (m & 0x00010000u) { if (pos < RCAP) rb[pos] = make_uint2((uint32_t)(4*n+2) | (s20 << 16), s21 | (s22 << 16)); pos++; }
    if (m & 0x01000000u) { if (pos < RCAP) rb[pos] = make_uint2((uint32_t)(4*n+3) | (s30 << 16), s31 | (s32 << 16)); pos++; }
  }
  if (n == 0) {
    #pragma unroll
    for (int b = 0; b < B_; ++b) {
      uint32_t tot = 0;
      for (int wq = 0; wq < 16; ++wq) tot += wsum[b][wq];
      actcnt[b * T_ + t] = tot;
    }
  }
}

// ---------------- kernel 3a: COMPACTED scan ----------------
// 8 blocks (one per batch). h as bytes in TRIPLE-rotated LDS buffers:
// step t: read buf[t%3], scatter-write buf[(t+1)%3] (pre-cleared at t-1),
// clear buf[(t+2)%3]. One barrier/step. Records (active neurons + their 3
// sources) are VMEM-prefetched one full step ahead (addresses independent of
// h -> latency fully hidden; this was the prior session's regression cause).
// Out row t-1 is read back coalesced from the stable read buffer.
// DS ops/step ~ 13 active waves x 8 + 4 clear + 16 readback = ~124 (was 208).
__global__ __launch_bounds__(1024) void scan_compact(const uint2* __restrict__ recs,
                                                     const uint32_t* __restrict__ actcnt,
                                                     const void* __restrict__ h0,
                                                     const uint32_t* __restrict__ modep,
                                                     uint32_t* __restrict__ out) {
  const int b = blockIdx.x;
  const int n = threadIdx.x;
  const int es = (int)modep[0];
  __shared__ __align__(16) unsigned char hb[3][4096];

  // init: buf0 = h(-1); buf1 = 0 (scatter target of step 0); buf2 cleared in step 0
  ((uint32_t*)hb[0])[n] = load4(h0, (long)b * 1024 + n, es);
  ((uint32_t*)hb[1])[n] = 0u;

  const uint2* recB = recs + (size_t)b * T_ * RCAP;
  uint32_t* outh = out + (long)b * T_ * 8192 + 4096;

  uint32_t cnt = min(actcnt[b * T_], (uint32_t)RCAP);
  uint4 pf = make_uint4(0, 0, 0, 0);
  if ((uint32_t)(2 * n) < cnt) pf = ((const uint4*)recB)[n];   // records 2n,2n+1 of t=0
  __syncthreads();

  for (int t = 0; t < T_; ++t) {
    const int rd = t % 3, wr = (t + 1) % 3, cl = (t + 2) % 3;
    const unsigned char* hc = hb[rd];
    unsigned char* hn = hb[wr];
    uint4 rec = pf;
    const uint32_t c = cnt;
    // prefetch next step's records (one full step of slack)
    if (t + 1 < T_) {
      cnt = min(actcnt[b * T_ + t + 1], (uint32_t)RCAP);
      if ((uint32_t)(2 * n) < cnt)
        pf = ((const uint4*)(recB + (size_t)(t + 1) * RCAP))[n];
    }
    // clear the buffer that was read last step (next step's scatter target)
    if (n < 256) ((uint4*)hb[cl])[n] = make_uint4(0, 0, 0, 0);
    // process my <=2 records (c is block-uniform -> wave-coherent branches)
    if ((uint32_t)(2 * n) < c) {
      uint32_t v = (uint32_t)hc[rec.x >> 16] | hc[rec.y & 0xFFFFu] | hc[rec.y >> 16];
      hn[rec.x & 0xFFFFu] = (unsigned char)v;
    }
    if ((uint32_t)(2 * n + 1) < c) {
      uint32_t v = (uint32_t)hc[rec.z >> 16] | hc[rec.w & 0xFFFFu] | hc[rec.w >> 16];
      hn[rec.z & 0xFFFFu] = (unsigned char)v;
    }
    // coalesced out write of row t-1 from the stable read buffer (VMEM pipe idle)
    if (t > 0) ((uint4*)(outh + (long)(t - 1) * 8192))[n] = expand01(((const uint32_t*)hc)[n]);
    __syncthreads();
  }
  // final row: h(T-1) sits in buf[T_ % 3]
  ((uint4*)(outh + (long)(T_ - 1) * 8192))[n] = expand01(((const uint32_t*)hb[T_ % 3])[n]);
}

// ---------------- kernel 3b: fallback scan (round-0 proven, 533 us) ----------
__global__ __launch_bounds__(1024) void scan_kernel(const uint32_t* __restrict__ in_orb,
                                                    const uint32_t* __restrict__ idxh,
                                                    const void* __restrict__ h0,
                                                    const uint32_t* __restrict__ modep,
                                                    uint32_t* __restrict__ out) {
  const int b = blockIdx.x;
  const int n = threadIdx.x;
  const int es = (int)modep[0];
  __shared__ __align__(16) unsigned char hbuf[2][4096];

  uint32_t d[4][3];
  {
    const uint4* p = (const uint4*)(idxh + n * 12);
    uint4 q0 = p[0], q1 = p[1], q2 = p[2];
    d[0][0] = q0.x; d[0][1] = q0.y; d[0][2] = q0.z;
    d[1][0] = q0.w; d[1][1] = q1.x; d[1][2] = q1.y;
    d[2][0] = q1.z; d[2][1] = q1.w; d[2][2] = q2.x;
    d[3][0] = q2.y; d[3][1] = q2.z; d[3][2] = q2.w;
  }
  ((uint32_t*)hbuf[0])[n] = load4(h0, (long)b * 1024 + n, es);
  __syncthreads();
  uint32_t* outh = out + (long)b * T_ * 8192 + 4096;
  int p = 0;
  uint32_t inw = in_orb[n];
  for (int t = 0; t < T_; ++t) {
    uint32_t inw_next = (t + 1 < T_) ? in_orb[(t + 1) * 1024 + n] : 0u;
    const unsigned char* hc = &hbuf[p][0];
    unsigned char* hn = &hbuf[p ^ 1][0];
    uint32_t mask = (inw >> b) & 0x01010101u;
    uint32_t out4 = 0;
    if (mask) {
      if (mask & 0x00000001u) { uint32_t v = (uint32_t)hc[d[0][0]] | hc[d[0][1]] | hc[d[0][2]]; out4 |= v; }
      if (mask & 0x00000100u) { uint32_t v = (uint32_t)hc[d[1][0]] | hc[d[1][1]] | hc[d[1][2]]; out4 |= v << 8; }
      if (mask & 0x00010000u) { uint32_t v = (uint32_t)hc[d[2][0]] | hc[d[2][1]] | hc[d[2][2]]; out4 |= v << 16; }
      if (mask & 0x01000000u) { uint32_t v = (uint32_t)hc[d[3][0]] | hc[d[3][1]] | hc[d[3][2]]; out4 |= v << 24; }
    }
    ((uint32_t*)hn)[n] = out4;
    ((uint4*)(outh + (long)t * 8192))[n] = expand01(out4);
    __syncthreads();
    inw = inw_next;
    p ^= 1;
  }
}

// ---------------- launch ----------------
extern "C" void kernel_launch(void* const* d_in, const int* in_sizes, int n_in,
                              void* d_out, int out_size, void* d_ws, size_t ws_size,
                              hipStream_t stream) {
  const void*  z   = d_in[0];                 // bool (B,T,CIN) - int32 0/1 (detected)
  const void*  h0  = d_in[1];                 // bool (B,CH)
  const float* Ain = (const float*)d_in[2];   // (CH,CIN) f32
  const float* Ah  = (const float*)d_in[3];   // (CH,CH)  f32
  uint32_t* out = (uint32_t*)d_out;           // int32 0/1

  char* ws = (char*)d_ws;
  // ws layout (bytes):
  // [0]       mode (256 reserved)
  // [256]     idx_in 48K
  // [49408]   idx_h  48K
  // [98560]   in_orb 4MiB                      -> end 4292864
  // [4292864] actcnt 32K (u32[8][1024])        -> end 4325632
  // [4325632] records uint2[8][1024][RCAP] = 120 MiB (compact mode only)
  uint32_t* modep = (uint32_t*)(ws);
  uint32_t* idxin = (uint32_t*)(ws + 256);
  uint32_t* idxh  = (uint32_t*)(ws + 256 + 49152);
  uint32_t* inorb = (uint32_t*)(ws + 98560);
  uint32_t* actc  = (uint32_t*)(ws + 4292864);
  uint2*    recs  = (uint2*)   (ws + 4325632);

  const size_t need = 4325632 + (size_t)B_ * T_ * RCAP * sizeof(uint2);
  const bool compact = (ws_size >= need);

  extract_kernel<<<2048 + 1, 256, 0, stream>>>(Ain, Ah, idxin, idxh,
                                               (const uint32_t*)z, modep);
  inor_kernel<<<T_, 1024, 0, stream>>>(z, idxin, idxh, modep, inorb, out,
                                       compact ? recs : nullptr, actc);
  if (compact)
    scan_compact<<<B_, 1024, 0, stream>>>(recs, actc, h0, modep, out);
  else
    scan_kernel<<<B_, 1024, 0, stream>>>(inorb, idxh, h0, modep, out);
}

// Round 3
// 1130.932 us; speedup vs baseline: 1.1994x; 1.0092x over previous
//
#include <hip/hip_runtime.h>
#include <stdint.h>

#define B_   8
#define T_   1024
#define CIN_ 4096
#define CH_  4096

// ---------------- helpers ----------------

// per-byte nonzero -> 0x01, packed
__device__ __forceinline__ uint32_t bytes_nonzero01(uint32_t w) {
  uint32_t t = (w & 0x7F7F7F7Fu) + 0x7F7F7F7Fu;
  t = (t | w) & 0x80808080u;
  return t >> 7;
}

// load 4 consecutive boolean elements (elements idx4*4 .. idx4*4+3) from a
// buffer whose element size is es (1, 2 or 4 bytes); return packed bytes 0/1.
__device__ __forceinline__ uint32_t load4(const void* base, long idx4, int es) {
  if (es == 1) {
    uint32_t w = ((const uint32_t*)base)[idx4];
    return bytes_nonzero01(w);
  } else if (es == 2) {
    uint32_t w0 = ((const uint32_t*)base)[idx4 * 2];
    uint32_t w1 = ((const uint32_t*)base)[idx4 * 2 + 1];
    uint32_t r = 0;
    r |= ((w0 & 0xFFFFu) != 0u) ? 0x00000001u : 0u;
    r |= ((w0 >> 16)     != 0u) ? 0x00000100u : 0u;
    r |= ((w1 & 0xFFFFu) != 0u) ? 0x00010000u : 0u;
    r |= ((w1 >> 16)     != 0u) ? 0x01000000u : 0u;
    return r;
  } else {
    uint4 w = ((const uint4*)base)[idx4];
    uint32_t r = 0;
    r |= (w.x != 0u) ? 0x00000001u : 0u;
    r |= (w.y != 0u) ? 0x00000100u : 0u;
    r |= (w.z != 0u) ? 0x00010000u : 0u;
    r |= (w.w != 0u) ? 0x01000000u : 0u;
    return r;
  }
}

// expand 4 packed 0/1 bytes into 4 int32 0/1
__device__ __forceinline__ uint4 expand01(uint32_t v4) {
  uint4 r = { v4 & 1u, (v4 >> 8) & 1u, (v4 >> 16) & 1u, (v4 >> 24) & 1u };
  return r;
}

// ---- device-scope producer/consumer handshake (cross-XCD safe) ----
// producer: all-thread stores -> __syncthreads (drains vmcnt per wave) ->
//           thread0 { __threadfence (L2 writeback) ; relaxed agent add }
// consumer: thread0 { relaxed agent spin ; __threadfence (invalidate) } -> __syncthreads
__device__ __forceinline__ void wait_ge(uint32_t* p, uint32_t tgt) {
  while (__hip_atomic_load(p, __ATOMIC_RELAXED, __HIP_MEMORY_SCOPE_AGENT) < tgt)
    __builtin_amdgcn_s_sleep(16);
  __threadfence();
}
__device__ __forceinline__ void bump(uint32_t* p) {
  __threadfence();
  __hip_atomic_fetch_add(p, 1u, __ATOMIC_RELAXED, __HIP_MEMORY_SCOPE_AGENT);
}

// ---------------- mega-kernel: all phases fused, flag-synced ----------------
// Round-2 lessons: (a) scan floor = 208 DS wave-ops/step (~5.8cyc each) — r0's
// formulation IS the floor (scheduling r1 and compaction r2 both failed to beat
// it); (b) the real waste is SERIALIZATION: extract+inor (~440us) run before a
// scan that uses 8/256 CUs. Fix: one launch. Scan blocks (bid 0..7, dispatched
// FIRST so they are resident immediately) spin on flags and chase the inor
// producers through in_orb in groups of 32 t's; extract / z-copy / in-OR run
// concurrently on the other CUs and are fully hidden behind the 533us scan.
// Deadlock-safe: only 8 blocks ever spin; all producers retire unconditionally.
//
// bid 0..7      : scan  (b = bid)                 waits: mode, idxh, group[t/32]
// bid 8         : detect (writes modep)           waits: none
// bid 9..264    : extract A_hidden rows 16/blk    waits: none   -> flags[2]
// bid 265..520  : extract A_input  rows 16/blk    waits: none   -> flags[1]
// bid 521..1544 : inor t = bid-521                waits: mode, idxin -> flags[8+t/32]
#define BID_DETECT 8
#define BID_EXT0   9
#define BID_INOR0  521
#define NBLK       (521 + T_)

__global__ __launch_bounds__(1024) void mega_kernel(const void* __restrict__ z,
                                                    const void* __restrict__ h0,
                                                    const float* __restrict__ Ain,
                                                    const float* __restrict__ Ah,
                                                    uint32_t* __restrict__ modep,
                                                    uint32_t* __restrict__ idxin,
                                                    uint32_t* __restrict__ idxh,
                                                    uint32_t* __restrict__ inorb,
                                                    uint32_t* __restrict__ flags,
                                                    uint32_t* __restrict__ out) {
  __shared__ __align__(16) unsigned char sm[2][4096];   // scan dbuf / inor zp
  __shared__ int cnt[16];                               // extract / detect scratch
  const int bid = blockIdx.x;
  const int n = threadIdx.x;

  if (bid < 8) {
    // ================= scan (r0-proven body + group gating) =================
    const int b = bid;
    if (n == 0) { wait_ge(&flags[0], 1); wait_ge(&flags[2], 256); }
    __syncthreads();
    const int es = (int)modep[0];
    uint32_t d[4][3];
    {
      const uint4* p = (const uint4*)(idxh + n * 12);
      uint4 q0 = p[0], q1 = p[1], q2 = p[2];
      d[0][0] = q0.x; d[0][1] = q0.y; d[0][2] = q0.z;
      d[1][0] = q0.w; d[1][1] = q1.x; d[1][2] = q1.y;
      d[2][0] = q1.z; d[2][1] = q1.w; d[2][2] = q2.x;
      d[3][0] = q2.y; d[3][1] = q2.z; d[3][2] = q2.w;
    }
    ((uint32_t*)sm[0])[n] = load4(h0, (long)b * 1024 + n, es);
    __syncthreads();
    uint32_t* outh = out + (long)b * T_ * 8192 + 4096;
    int p = 0;
    for (int g = 0; g < 32; ++g) {
      if (n == 0) wait_ge(&flags[8 + g], 32);   // in_orb rows g*32..g*32+31 ready
      __syncthreads();
      uint32_t inw = inorb[(g * 32) * 1024 + n];
      for (int tt = 0; tt < 32; ++tt) {
        const int t = g * 32 + tt;
        uint32_t inw_next = (tt < 31) ? inorb[(t + 1) * 1024 + n] : 0u;
        const unsigned char* hc = &sm[p][0];
        unsigned char* hn = &sm[p ^ 1][0];
        uint32_t mask = (inw >> b) & 0x01010101u;
        uint32_t o4 = 0;
        if (mask) {
          if (mask & 0x00000001u) { uint32_t v = (uint32_t)hc[d[0][0]] | hc[d[0][1]] | hc[d[0][2]]; o4 |= v; }
          if (mask & 0x00000100u) { uint32_t v = (uint32_t)hc[d[1][0]] | hc[d[1][1]] | hc[d[1][2]]; o4 |= v << 8; }
          if (mask & 0x00010000u) { uint32_t v = (uint32_t)hc[d[2][0]] | hc[d[2][1]] | hc[d[2][2]]; o4 |= v << 16; }
          if (mask & 0x01000000u) { uint32_t v = (uint32_t)hc[d[3][0]] | hc[d[3][1]] | hc[d[3][2]]; o4 |= v << 24; }
        }
        ((uint32_t*)hn)[n] = o4;
        ((uint4*)(outh + (long)t * 8192))[n] = expand01(o4);   // fire-and-forget
        __syncthreads();
        inw = inw_next;
        p ^= 1;
      }
    }
    return;
  }

  if (bid == BID_DETECT) {
    // ================= encoding detection (threads 0..255) =================
    if (n == 0) { cnt[0] = 1; cnt[1] = 1; cnt[2] = 1; cnt[3] = 0; }
    __syncthreads();
    if (n < 256) {
      const uint32_t* zw = (const uint32_t*)z;
      int okB = 1, okH = 1, okW = 1, low = 0;
      for (int k = 0; k < 16; ++k) {
        uint32_t w = zw[n + 256 * k];
        if ((w & 0xFEFEFEFEu) != 0u) okB = 0;
        uint32_t lo = w & 0xFFFFu, hi = w >> 16;
        if (!((lo == 0u || lo == 0x3F80u) && (hi == 0u || hi == 0x3F80u))) okH = 0;
        if (!(w == 0u || w == 1u)) okW = 0;
        if (lo != 0u) low = 1;
      }
      if (!okB) atomicAnd(&cnt[0], 0);
      if (!okH) atomicAnd(&cnt[1], 0);
      if (!okW) atomicAnd(&cnt[2], 0);
      if (low)  atomicOr(&cnt[3], 1);
    }
    __syncthreads();
    if (n == 0) {
      uint32_t mode;
      if (cnt[2])      mode = 4;              // int32 0/1
      else if (cnt[0]) mode = 1;              // uint8 bool
      else if (cnt[1]) mode = cnt[3] ? 2 : 4; // bf16 : float32
      else             mode = 1;
      modep[0] = mode;
      bump(&flags[0]);
    }
    return;
  }

  if (bid < BID_INOR0) {
    // ================= fan-in extraction, 16 rows/block =================
    const int eb = bid - BID_EXT0;            // 0..511; <256 = hidden (first!)
    const int wave = n >> 6, lane = n & 63;
    const int isH = (eb < 256);
    const int row = (isH ? eb : eb - 256) * 16 + wave;   // 0..4095
    const float* A = (isH ? Ah : Ain) + (long)row * 4096;
    uint32_t* outp = (isH ? idxh : idxin) + row * 3;
    if (lane == 0) cnt[wave] = 0;
    __syncthreads();
    const float4* A4 = (const float4*)A;
    #pragma unroll
    for (int it = 0; it < 16; ++it) {
      float4 v = A4[it * 64 + lane];
      int cbase = (it * 64 + lane) * 4;
      if (v.x != 0.0f) { int q = atomicAdd(&cnt[wave], 1); if (q < 3) outp[q] = cbase;     }
      if (v.y != 0.0f) { int q = atomicAdd(&cnt[wave], 1); if (q < 3) outp[q] = cbase + 1; }
      if (v.z != 0.0f) { int q = atomicAdd(&cnt[wave], 1); if (q < 3) outp[q] = cbase + 2; }
      if (v.w != 0.0f) { int q = atomicAdd(&cnt[wave], 1); if (q < 3) outp[q] = cbase + 3; }
    }
    __syncthreads();
    if (n == 0) bump(isH ? &flags[2] : &flags[1]);
    return;
  }

  // ================= in-OR + z-copy (t = bid - BID_INOR0) =================
  {
    const int t = bid - BID_INOR0;
    if (n == 0) { wait_ge(&flags[0], 1); wait_ge(&flags[1], 256); }
    __syncthreads();
    const int es = (int)modep[0];
    uint32_t acc = 0;
    #pragma unroll
    for (int b = 0; b < B_; ++b) {
      uint32_t v4 = load4(z, ((long)b * T_ + t) * 1024 + n, es);
      acc |= v4 << b;
      ((uint4*)(out + ((long)b * T_ + t) * 8192))[n] = expand01(v4);
    }
    ((uint32_t*)sm[0])[n] = acc;
    __syncthreads();
    const unsigned char* zp = &sm[0][0];
    const uint4* ip = (const uint4*)(idxin + n * 12);
    uint4 q0 = ip[0], q1 = ip[1], q2 = ip[2];
    uint32_t r0 = (uint32_t)zp[q0.x] | zp[q0.y] | zp[q0.z];
    uint32_t r1 = (uint32_t)zp[q0.w] | zp[q1.x] | zp[q1.y];
    uint32_t r2 = (uint32_t)zp[q1.z] | zp[q1.w] | zp[q2.x];
    uint32_t r3 = (uint32_t)zp[q2.y] | zp[q2.z] | zp[q2.w];
    inorb[t * 1024 + n] = r0 | (r1 << 8) | (r2 << 16) | (r3 << 24);
    __syncthreads();
    if (n == 0) bump(&flags[8 + (t >> 5)]);
    return;
  }
}

// ---------------- launch ----------------
extern "C" void kernel_launch(void* const* d_in, const int* in_sizes, int n_in,
                              void* d_out, int out_size, void* d_ws, size_t ws_size,
                              hipStream_t stream) {
  const void*  z   = d_in[0];                 // bool (B,T,CIN) - int32 0/1 (detected)
  const void*  h0  = d_in[1];                 // bool (B,CH)
  const float* Ain = (const float*)d_in[2];   // (CH,CIN) f32
  const float* Ah  = (const float*)d_in[3];   // (CH,CH)  f32
  uint32_t* out = (uint32_t*)d_out;           // int32 0/1

  char* ws = (char*)d_ws;
  // ws layout (bytes):
  // [0]       mode (256 reserved)
  // [256]     idx_in 48K
  // [49408]   idx_h  48K
  // [98560]   in_orb 4MiB                      -> end 4292864
  // [4292864] flags 4K: [0] mode_done, [1] ctr_idxin, [2] ctr_idxh,
  //                     [8+g] inor group counters (g = t/32, each -> 32)
  uint32_t* modep = (uint32_t*)(ws);
  uint32_t* idxin = (uint32_t*)(ws + 256);
  uint32_t* idxh  = (uint32_t*)(ws + 256 + 49152);
  uint32_t* inorb = (uint32_t*)(ws + 98560);
  uint32_t* flagp = (uint32_t*)(ws + 4292864);

  hipMemsetAsync(flagp, 0, 4096, stream);     // graph-capture-safe, stream-ordered
  mega_kernel<<<NBLK, 1024, 0, stream>>>(z, h0, Ain, Ah, modep, idxin, idxh,
                                         inorb, flagp, out);
}

// Round 4
// 1126.991 us; speedup vs baseline: 1.2035x; 1.0035x over previous
//
#include <hip/hip_runtime.h>
#include <stdint.h>

#define B_   8
#define T_   1024
#define CIN_ 4096
#define CH_  4096
#define GRP  16              // in_orb chase-group size (t's per flag)
#define NGRP (T_ / GRP)

// ---------------- helpers ----------------

// per-byte nonzero -> 0x01, packed
__device__ __forceinline__ uint32_t bytes_nonzero01(uint32_t w) {
  uint32_t t = (w & 0x7F7F7F7Fu) + 0x7F7F7F7Fu;
  t = (t | w) & 0x80808080u;
  return t >> 7;
}

// load 4 consecutive boolean elements (elements idx4*4 .. idx4*4+3) from a
// buffer whose element size is es (1, 2 or 4 bytes); return packed bytes 0/1.
__device__ __forceinline__ uint32_t load4(const void* base, long idx4, int es) {
  if (es == 1) {
    uint32_t w = ((const uint32_t*)base)[idx4];
    return bytes_nonzero01(w);
  } else if (es == 2) {
    uint32_t w0 = ((const uint32_t*)base)[idx4 * 2];
    uint32_t w1 = ((const uint32_t*)base)[idx4 * 2 + 1];
    uint32_t r = 0;
    r |= ((w0 & 0xFFFFu) != 0u) ? 0x00000001u : 0u;
    r |= ((w0 >> 16)     != 0u) ? 0x00000100u : 0u;
    r |= ((w1 & 0xFFFFu) != 0u) ? 0x00010000u : 0u;
    r |= ((w1 >> 16)     != 0u) ? 0x01000000u : 0u;
    return r;
  } else {
    uint4 w = ((const uint4*)base)[idx4];
    uint32_t r = 0;
    r |= (w.x != 0u) ? 0x00000001u : 0u;
    r |= (w.y != 0u) ? 0x00000100u : 0u;
    r |= (w.z != 0u) ? 0x00010000u : 0u;
    r |= (w.w != 0u) ? 0x01000000u : 0u;
    return r;
  }
}

// expand 4 packed 0/1 bytes into 4 int32 0/1
__device__ __forceinline__ uint4 expand01(uint32_t v4) {
  uint4 r = { v4 & 1u, (v4 >> 8) & 1u, (v4 >> 16) & 1u, (v4 >> 24) & 1u };
  return r;
}

// ---- device-scope producer/consumer handshake (cross-XCD safe, r3-proven) ----
__device__ __forceinline__ void wait_ge(uint32_t* p, uint32_t tgt) {
  while (__hip_atomic_load(p, __ATOMIC_RELAXED, __HIP_MEMORY_SCOPE_AGENT) < tgt)
    __builtin_amdgcn_s_sleep(2);
  __threadfence();
}
__device__ __forceinline__ void bump(uint32_t* p) {
  __threadfence();
  __hip_atomic_fetch_add(p, 1u, __ATOMIC_RELAXED, __HIP_MEMORY_SCOPE_AGENT);
}

// ---------------- mega-kernel: all phases fused, flag-synced ----------------
// r3 post-mortem: fusion worked but mega=838us vs scan-floor 533. Cause: with
// 8.7KB LDS the HW co-schedules 2 blocks/CU, so producer blocks (13 DS-ops/
// thread in-OR gathers) share the scan CUs' DS pipe — the exact pipe the scan
// floor (208 DS wave-ops/step x ~5.8cyc) lives on. Fix: 88KiB static LDS ->
// 1 block/CU BY CONSTRUCTION (88*2 > 160). Scan CUs become exclusive; the
// producers get 248 CUs (their total work ~60-80us, hidden under the scan).
// Order fix: input-extract FIRST (idxin gates inor gates scan group 0; idxh
// only gates scan register setup).
//
// bid 0..7      : scan  (b = bid)               waits: mode, idxh, group[t/16]
// bid 8         : detect (writes modep)         waits: none
// bid 9..264    : extract A_input  rows 16/blk  waits: none -> flags[1]
// bid 265..520  : extract A_hidden rows 16/blk  waits: none -> flags[2]
// bid 521..1544 : inor t = bid-521              waits: mode, idxin -> flags[8+t/16]
#define BID_DETECT 8
#define BID_EXTIN0 9
#define BID_EXTH0  265
#define BID_INOR0  521
#define NBLK       (521 + T_)

__global__ __launch_bounds__(1024) void mega_kernel(const void* __restrict__ z,
                                                    const void* __restrict__ h0,
                                                    const float* __restrict__ Ain,
                                                    const float* __restrict__ Ah,
                                                    uint32_t* __restrict__ modep,
                                                    uint32_t* __restrict__ idxin,
                                                    uint32_t* __restrict__ idxh,
                                                    uint32_t* __restrict__ inorb,
                                                    uint32_t* __restrict__ flags,
                                                    uint32_t* __restrict__ out) {
  // 88 KiB: forces 1 block/CU (exclusive DS pipe for scan blocks). All
  // phase-local buffers are carved from it so it can't be optimized away.
  __shared__ __align__(16) unsigned char smem[88 * 1024];
  unsigned char* sm0 = &smem[0];            // scan dbuf[0] / inor zp
  unsigned char* sm1 = &smem[4096];         // scan dbuf[1]
  int* scnt = (int*)&smem[8192];            // extract/detect scratch (16 ints)
  const int bid = blockIdx.x;
  const int n = threadIdx.x;

  if (bid < 8) {
    // ================= scan (r0-proven body, exclusive CU) =================
    __builtin_amdgcn_s_setprio(1);          // insurance vs any transient co-resident
    const int b = bid;
    if (n == 0) wait_ge(&flags[0], 1);      // mode ready
    __syncthreads();
    const int es = (int)modep[0];
    ((uint32_t*)sm0)[n] = load4(h0, (long)b * 1024 + n, es);
    if (n == 0) wait_ge(&flags[2], 256);    // idxh ready
    __syncthreads();
    uint32_t d[4][3];
    {
      const uint4* p = (const uint4*)(idxh + n * 12);
      uint4 q0 = p[0], q1 = p[1], q2 = p[2];
      d[0][0] = q0.x; d[0][1] = q0.y; d[0][2] = q0.z;
      d[1][0] = q0.w; d[1][1] = q1.x; d[1][2] = q1.y;
      d[2][0] = q1.z; d[2][1] = q1.w; d[2][2] = q2.x;
      d[3][0] = q2.y; d[3][1] = q2.z; d[3][2] = q2.w;
    }
    __syncthreads();
    uint32_t* outh = out + (long)b * T_ * 8192 + 4096;
    int p = 0;
    for (int g = 0; g < NGRP; ++g) {
      if (n == 0) wait_ge(&flags[8 + g], GRP);   // in_orb t = g*GRP .. +GRP-1 ready
      __syncthreads();
      uint32_t inw = inorb[(g * GRP) * 1024 + n];
      for (int tt = 0; tt < GRP; ++tt) {
        const int t = g * GRP + tt;
        uint32_t inw_next = (tt < GRP - 1) ? inorb[(t + 1) * 1024 + n] : 0u;
        const unsigned char* hc = p ? sm1 : sm0;
        unsigned char* hn = p ? sm0 : sm1;
        uint32_t mask = (inw >> b) & 0x01010101u;
        uint32_t o4 = 0;
        if (mask) {
          if (mask & 0x00000001u) { uint32_t v = (uint32_t)hc[d[0][0]] | hc[d[0][1]] | hc[d[0][2]]; o4 |= v; }
          if (mask & 0x00000100u) { uint32_t v = (uint32_t)hc[d[1][0]] | hc[d[1][1]] | hc[d[1][2]]; o4 |= v << 8; }
          if (mask & 0x00010000u) { uint32_t v = (uint32_t)hc[d[2][0]] | hc[d[2][1]] | hc[d[2][2]]; o4 |= v << 16; }
          if (mask & 0x01000000u) { uint32_t v = (uint32_t)hc[d[3][0]] | hc[d[3][1]] | hc[d[3][2]]; o4 |= v << 24; }
        }
        ((uint32_t*)hn)[n] = o4;
        ((uint4*)(outh + (long)t * 8192))[n] = expand01(o4);   // fire-and-forget
        __syncthreads();
        inw = inw_next;
        p ^= 1;
      }
    }
    return;
  }

  if (bid == BID_DETECT) {
    // ================= encoding detection (all 1024 threads) =================
    if (n == 0) { scnt[0] = 1; scnt[1] = 1; scnt[2] = 1; scnt[3] = 0; }
    __syncthreads();
    {
      const uint32_t* zw = (const uint32_t*)z;
      int okB = 1, okH = 1, okW = 1, low = 0;
      #pragma unroll
      for (int k = 0; k < 4; ++k) {
        uint32_t w = zw[n + 1024 * k];
        if ((w & 0xFEFEFEFEu) != 0u) okB = 0;
        uint32_t lo = w & 0xFFFFu, hi = w >> 16;
        if (!((lo == 0u || lo == 0x3F80u) && (hi == 0u || hi == 0x3F80u))) okH = 0;
        if (!(w == 0u || w == 1u)) okW = 0;
        if (lo != 0u) low = 1;
      }
      if (!okB) atomicAnd(&scnt[0], 0);
      if (!okH) atomicAnd(&scnt[1], 0);
      if (!okW) atomicAnd(&scnt[2], 0);
      if (low)  atomicOr(&scnt[3], 1);
    }
    __syncthreads();
    if (n == 0) {
      uint32_t mode;
      if (scnt[2])      mode = 4;               // int32 0/1
      else if (scnt[0]) mode = 1;               // uint8 bool
      else if (scnt[1]) mode = scnt[3] ? 2 : 4; // bf16 : float32
      else              mode = 1;
      modep[0] = mode;
      bump(&flags[0]);
    }
    return;
  }

  if (bid < BID_INOR0) {
    // ================= fan-in extraction, 16 rows/block =================
    const int isIn = (bid < BID_EXTH0);
    const int eb = isIn ? (bid - BID_EXTIN0) : (bid - BID_EXTH0);  // 0..255
    const int wave = n >> 6, lane = n & 63;
    const int row = eb * 16 + wave;                                // 0..4095
    const float* A = (isIn ? Ain : Ah) + (long)row * 4096;
    uint32_t* outp = (isIn ? idxin : idxh) + row * 3;
    if (lane == 0) scnt[wave] = 0;
    __syncthreads();
    const float4* A4 = (const float4*)A;
    #pragma unroll
    for (int it = 0; it < 16; ++it) {
      float4 v = A4[it * 64 + lane];
      int cbase = (it * 64 + lane) * 4;
      if (v.x != 0.0f) { int q = atomicAdd(&scnt[wave], 1); if (q < 3) outp[q] = cbase;     }
      if (v.y != 0.0f) { int q = atomicAdd(&scnt[wave], 1); if (q < 3) outp[q] = cbase + 1; }
      if (v.z != 0.0f) { int q = atomicAdd(&scnt[wave], 1); if (q < 3) outp[q] = cbase + 2; }
      if (v.w != 0.0f) { int q = atomicAdd(&scnt[wave], 1); if (q < 3) outp[q] = cbase + 3; }
    }
    __syncthreads();
    if (n == 0) bump(isIn ? &flags[1] : &flags[2]);
    return;
  }

  // ================= in-OR + z-copy (t = bid - BID_INOR0) =================
  {
    const int t = bid - BID_INOR0;
    if (n == 0) { wait_ge(&flags[0], 1); wait_ge(&flags[1], 256); }
    __syncthreads();
    const int es = (int)modep[0];
    uint32_t acc = 0;
    #pragma unroll
    for (int b = 0; b < B_; ++b) {
      uint32_t v4 = load4(z, ((long)b * T_ + t) * 1024 + n, es);
      acc |= v4 << b;
      ((uint4*)(out + ((long)b * T_ + t) * 8192))[n] = expand01(v4);
    }
    ((uint32_t*)sm0)[n] = acc;
    __syncthreads();
    const unsigned char* zp = sm0;
    const uint4* ip = (const uint4*)(idxin + n * 12);
    uint4 q0 = ip[0], q1 = ip[1], q2 = ip[2];
    uint32_t r0 = (uint32_t)zp[q0.x] | zp[q0.y] | zp[q0.z];
    uint32_t r1 = (uint32_t)zp[q0.w] | zp[q1.x] | zp[q1.y];
    uint32_t r2 = (uint32_t)zp[q1.z] | zp[q1.w] | zp[q2.x];
    uint32_t r3 = (uint32_t)zp[q2.y] | zp[q2.z] | zp[q2.w];
    inorb[t * 1024 + n] = r0 | (r1 << 8) | (r2 << 16) | (r3 << 24);
    __syncthreads();
    if (n == 0) bump(&flags[8 + (t >> 4)]);
    return;
  }
}

// ---------------- launch ----------------
extern "C" void kernel_launch(void* const* d_in, const int* in_sizes, int n_in,
                              void* d_out, int out_size, void* d_ws, size_t ws_size,
                              hipStream_t stream) {
  const void*  z   = d_in[0];                 // bool (B,T,CIN) - int32 0/1 (detected)
  const void*  h0  = d_in[1];                 // bool (B,CH)
  const float* Ain = (const float*)d_in[2];   // (CH,CIN) f32
  const float* Ah  = (const float*)d_in[3];   // (CH,CH)  f32
  uint32_t* out = (uint32_t*)d_out;           // int32 0/1

  char* ws = (char*)d_ws;
  // ws layout (bytes):
  // [0]       mode (256 reserved)
  // [256]     idx_in 48K
  // [49408]   idx_h  48K
  // [98560]   in_orb 4MiB                      -> end 4292864
  // [4292864] flags 4K: [0] mode_done, [1] ctr_idxin, [2] ctr_idxh,
  //                     [8+g] inor group counters (g = t/GRP, each -> GRP)
  uint32_t* modep = (uint32_t*)(ws);
  uint32_t* idxin = (uint32_t*)(ws + 256);
  uint32_t* idxh  = (uint32_t*)(ws + 256 + 49152);
  uint32_t* inorb = (uint32_t*)(ws + 98560);
  uint32_t* flagp = (uint32_t*)(ws + 4292864);

  hipMemsetAsync(flagp, 0, 4096, stream);     // graph-capture-safe, stream-ordered
  mega_kernel<<<NBLK, 1024, 0, stream>>>(z, h0, Ain, Ah, modep, idxin, idxh,
                                         inorb, flagp, out);
}